// Round 9
// baseline (2493.268 us; speedup 1.0000x reference)
//
#include <hip/hip_runtime.h>

constexpr int D = 64;
constexpr int NBUK = 1024;          // dst buckets == aggregate grid (4 blocks/CU)
constexpr int MAXROWS = 150;        // max nodes/bucket (supports N <= 153600)
constexpr int NBAND = 10;           // src>>14 bands (N <= 163840)
constexpr int NBIN2 = NBAND << 8;   // fine bins: (band<<8) | local_dst
constexpr int TILE_E = 4096;        // edges per scatter block (512 thr x 8)

typedef __attribute__((ext_vector_type(8))) short short8;   // 8 bf16 (4 VGPRs)
typedef __attribute__((ext_vector_type(4))) float f32x4;

__device__ inline unsigned short f2bf(float f) {   // RNE f32->bf16
    unsigned int u = __float_as_uint(f);
    u += 0x7FFFu + ((u >> 16) & 1u);
    return (unsigned short)(u >> 16);
}
__device__ inline float bf2f(unsigned short s) {
    return __uint_as_float(((unsigned int)s) << 16);
}
// bucket(dst) = floor(dst*1024/N) via magic mul; M = ceil(2^48/N) (host-computed)
__device__ inline int bucket_of(int dst, unsigned long long M) {
    return (int)((((unsigned long long)dst << 10) * M) >> 48);
}
__device__ inline int bstart(int b, int N) {   // first node of bucket b
    return (int)(((long long)b * N + 1023) >> 10);
}

// ---------- 1. histogram of dst buckets ----------
__global__ __launch_bounds__(256) void k_bucket_hist(const int* __restrict__ ei,
                                                     int* __restrict__ bcount,
                                                     int E, unsigned long long M) {
    __shared__ int h[NBUK];
    for (int i = threadIdx.x; i < NBUK; i += 256) h[i] = 0;
    __syncthreads();
    int stride = gridDim.x * blockDim.x;
    for (int e = blockIdx.x * blockDim.x + threadIdx.x; e < E; e += stride)
        atomicAdd(&h[bucket_of(ei[E + e], M)], 1);
    __syncthreads();
    for (int i = threadIdx.x; i < NBUK; i += 256)
        if (h[i]) atomicAdd(&bcount[i], h[i]);
}

// ---------- 2. scan 1024 bucket counts -> bbase; zero gfill ----------
__global__ __launch_bounds__(512) void k_scan_buckets(const int* __restrict__ bcount,
                                                      int* __restrict__ bbase,
                                                      int* __restrict__ gfill, int E) {
    __shared__ int sc[512];
    __shared__ int carry;
    const int tid = threadIdx.x;
    if (tid == 0) carry = 0;
    __syncthreads();
    for (int c = 0; c < NBUK / 512; ++c) {
        int i = c * 512 + tid;
        int v = bcount[i];
        sc[tid] = v;
        __syncthreads();
        for (int off = 1; off < 512; off <<= 1) {
            int t = (tid >= off) ? sc[tid - off] : 0;
            __syncthreads();
            sc[tid] += t;
            __syncthreads();
        }
        bbase[i] = carry + sc[tid] - v;
        gfill[i] = 0;
        __syncthreads();
        if (tid == 0) carry += sc[511];
        __syncthreads();
    }
    if (tid == 0) bbase[NBUK] = E;
}

// ---------- 3. scatter edges into buckets: packed = (local_dst<<18) | src ----------
__global__ __launch_bounds__(512) void k_bucket_scatter(const int* __restrict__ ei,
                                                        const int* __restrict__ bbase,
                                                        int* __restrict__ gfill,
                                                        unsigned int* __restrict__ packed,
                                                        int E, unsigned long long M, int N) {
    __shared__ int hist[NBUK], base[NBUK], fil[NBUK];
    const int tid = threadIdx.x;
    for (int i = tid; i < NBUK; i += 512) hist[i] = 0;
    __syncthreads();

    const int t0 = blockIdx.x * TILE_E;
    int bk[8];
    unsigned int vv[8];
#pragma unroll
    for (int j = 0; j < 8; ++j) {
        int e = t0 + tid + j * 512;
        bk[j] = -1;
        if (e < E) {
            int src = ei[e];
            int dst = ei[E + e];
            int b = bucket_of(dst, M);
            bk[j] = b;
            vv[j] = ((unsigned int)(dst - bstart(b, N)) << 18) | (unsigned int)src;
            atomicAdd(&hist[b], 1);
        }
    }
    __syncthreads();
    for (int i = tid; i < NBUK; i += 512) {
        if (hist[i]) base[i] = atomicAdd(&gfill[i], hist[i]);
        fil[i] = 0;
    }
    __syncthreads();
#pragma unroll
    for (int j = 0; j < 8; ++j) {
        if (bk[j] >= 0) {
            int b = bk[j];
            int pos = bbase[b] + base[b] + atomicAdd(&fil[b], 1);
            packed[pos] = vv[j];
        }
    }
}

// ---------- 4. per-bucket counting sort by (band, local_dst); dinv ----------
__global__ __launch_bounds__(256) void k_build_fine(const unsigned int* __restrict__ packed,
                                                    const int* __restrict__ bbase,
                                                    float* __restrict__ dinv,
                                                    unsigned int* __restrict__ csr_pk,
                                                    int N) {
    __shared__ int hist[NBIN2], fil[NBIN2], part[256];
    const int b = blockIdx.x;
    const int s = bbase[b], t = bbase[b + 1];
    const int tid = threadIdx.x;
    const int rs = bstart(b, N);
    const int rows = bstart(b + 1, N) - rs;

    for (int i = tid; i < NBIN2; i += 256) hist[i] = 0;
    __syncthreads();
    for (int e = s + tid; e < t; e += 256) {
        unsigned int v = packed[e];
        int key = (int)(((v & 0x3FFFFu) >> 14) << 8) | (int)(v >> 18);
        atomicAdd(&hist[key], 1);
    }
    __syncthreads();

    // degree -> dinv (reads counts before scan overwrites)
    for (int ld = tid; ld < rows; ld += 256) {
        int deg = 0;
#pragma unroll
        for (int band = 0; band < NBAND; ++band) deg += hist[(band << 8) | ld];
        dinv[rs + ld] = rsqrtf((float)(deg + 1));   // +1 self-loop
    }
    const int base = tid * (NBIN2 / 256);
    int lsum = 0;
#pragma unroll
    for (int i = 0; i < NBIN2 / 256; ++i) lsum += hist[base + i];
    part[tid] = lsum;
    __syncthreads();
    for (int off = 1; off < 256; off <<= 1) {
        int tv = (tid >= off) ? part[tid - off] : 0;
        __syncthreads();
        part[tid] += tv;
        __syncthreads();
    }
    int run = part[tid] - lsum;   // exclusive prefix of this thread's chunk
#pragma unroll
    for (int i = 0; i < NBIN2 / 256; ++i) {
        int h = hist[base + i];
        hist[base + i] = run;     // hist becomes exclusive scan
        run += h;
    }
    for (int i = tid; i < NBIN2; i += 256) fil[i] = 0;
    __syncthreads();

    for (int e = s + tid; e < t; e += 256) {
        unsigned int v = packed[e];
        int key = (int)(((v & 0x3FFFFu) >> 14) << 8) | (int)(v >> 18);
        int pos = s + hist[key] + atomicAdd(&fil[key], 1);
        csr_pk[pos] = v;
    }
}

// ------- MFMA GEMM: hs_out = bf16((xin @ W)*dinv); layer 0 also acc = x0 -------
template <bool F32IN>
__global__ __launch_bounds__(256) void k_gemm(const float* __restrict__ u,
                                              const float* __restrict__ it,
                                              int U,
                                              const unsigned short* __restrict__ xin16,
                                              const float* __restrict__ W,
                                              const float* __restrict__ dinv,
                                              unsigned short* __restrict__ hs_out,
                                              float* __restrict__ acc,
                                              int N) {
    const int lane = threadIdx.x & 63;
    const int g = lane >> 4;
    const int lr = lane & 15;

    short8 bf[4][2];
#pragma unroll
    for (int ct = 0; ct < 4; ++ct)
#pragma unroll
        for (int kb = 0; kb < 2; ++kb) {
            short8 v;
            int c = ct * 16 + lr;
#pragma unroll
            for (int e = 0; e < 4; ++e) {
                int k0 = kb * 32 + g * 4 + e;
                v[e]     = (short)f2bf(W[k0 * D + c]);
                v[e + 4] = (short)f2bf(W[(k0 + 16) * D + c]);
            }
            bf[ct][kb] = v;
        }

    const int wid = blockIdx.x * (blockDim.x >> 6) + (threadIdx.x >> 6);
    const int nw = gridDim.x * (blockDim.x >> 6);

    for (int rb = wid * 16; rb < N; rb += nw * 16) {
        int row = rb + lr;
        bool ok = (row < N);
        short8 af[2];
        if (F32IN) {
            const float* xr = nullptr;
            if (ok) xr = (row < U) ? (u + (size_t)row * D)
                                   : (it + (size_t)(row - U) * D);
#pragma unroll
            for (int kb = 0; kb < 2; ++kb) {
                float4 q0 = ok ? *(const float4*)(xr + kb * 32 + g * 4)
                               : float4{0.f, 0.f, 0.f, 0.f};
                float4 q1 = ok ? *(const float4*)(xr + kb * 32 + 16 + g * 4)
                               : float4{0.f, 0.f, 0.f, 0.f};
                if (ok) {   // acc = x0
                    *(float4*)(acc + (size_t)row * D + kb * 32 + g * 4) = q0;
                    *(float4*)(acc + (size_t)row * D + kb * 32 + 16 + g * 4) = q1;
                }
                short8 v;
                v[0] = (short)f2bf(q0.x); v[1] = (short)f2bf(q0.y);
                v[2] = (short)f2bf(q0.z); v[3] = (short)f2bf(q0.w);
                v[4] = (short)f2bf(q1.x); v[5] = (short)f2bf(q1.y);
                v[6] = (short)f2bf(q1.z); v[7] = (short)f2bf(q1.w);
                af[kb] = v;
            }
        } else {
            const unsigned short* xr = xin16 + (size_t)row * D;
#pragma unroll
            for (int kb = 0; kb < 2; ++kb) {
                short4 q0 = ok ? *(const short4*)(xr + kb * 32 + g * 4)
                               : short4{0, 0, 0, 0};
                short4 q1 = ok ? *(const short4*)(xr + kb * 32 + 16 + g * 4)
                               : short4{0, 0, 0, 0};
                short8 v;
                v[0] = q0.x; v[1] = q0.y; v[2] = q0.z; v[3] = q0.w;
                v[4] = q1.x; v[5] = q1.y; v[6] = q1.z; v[7] = q1.w;
                af[kb] = v;
            }
        }

        float di[4];
#pragma unroll
        for (int r = 0; r < 4; ++r) {
            int ro = rb + g * 4 + r;
            di[r] = (ro < N) ? dinv[ro] : 0.f;
        }

#pragma unroll
        for (int ct = 0; ct < 4; ++ct) {
            f32x4 a = {0.f, 0.f, 0.f, 0.f};
            a = __builtin_amdgcn_mfma_f32_16x16x32_bf16(af[0], bf[ct][0], a, 0, 0, 0);
            a = __builtin_amdgcn_mfma_f32_16x16x32_bf16(af[1], bf[ct][1], a, 0, 0, 0);
#pragma unroll
            for (int r = 0; r < 4; ++r) {
                int ro = rb + g * 4 + r;
                if (ro < N)
                    hs_out[(size_t)ro * D + ct * 16 + lr] = f2bf(a[r] * di[r]);
            }
        }
    }
}

// ------- 5. edge-parallel LDS aggregate: block = bucket, band-coherent sweep -------
template <bool LAST>
__global__ __launch_bounds__(512, 8) void k_agg_lds(const unsigned int* __restrict__ csr_pk,
                                                    const int* __restrict__ bbase,
                                                    const unsigned short* __restrict__ hs16,
                                                    const float* __restrict__ dinv,
                                                    const float* __restrict__ bias,
                                                    unsigned short* __restrict__ val16,
                                                    float* __restrict__ acc,
                                                    float scale, int N) {
    __shared__ float accs[MAXROWS * D];   // 38400 B -> 4 blocks/CU
    const int b = blockIdx.x;
    const int s = bbase[b], t = bbase[b + 1];
    const int rs = bstart(b, N);
    const int rows = bstart(b + 1, N) - rs;
    const int tid = threadIdx.x;
    for (int i = tid; i < rows * D; i += 512) accs[i] = 0.f;
    __syncthreads();

    const int w = tid >> 6, lane = tid & 63;
    for (int e0 = s + w * 8; e0 < t; e0 += 64) {
        int n = t - e0;
        if (n >= 8) {
            unsigned int p0 = csr_pk[e0 + 0], p1 = csr_pk[e0 + 1];
            unsigned int p2 = csr_pk[e0 + 2], p3 = csr_pk[e0 + 3];
            unsigned int p4 = csr_pk[e0 + 4], p5 = csr_pk[e0 + 5];
            unsigned int p6 = csr_pk[e0 + 6], p7 = csr_pk[e0 + 7];
            float g0 = bf2f(hs16[(size_t)(p0 & 0x3FFFFu) * D + lane]);
            float g1 = bf2f(hs16[(size_t)(p1 & 0x3FFFFu) * D + lane]);
            float g2 = bf2f(hs16[(size_t)(p2 & 0x3FFFFu) * D + lane]);
            float g3 = bf2f(hs16[(size_t)(p3 & 0x3FFFFu) * D + lane]);
            float g4 = bf2f(hs16[(size_t)(p4 & 0x3FFFFu) * D + lane]);
            float g5 = bf2f(hs16[(size_t)(p5 & 0x3FFFFu) * D + lane]);
            float g6 = bf2f(hs16[(size_t)(p6 & 0x3FFFFu) * D + lane]);
            float g7 = bf2f(hs16[(size_t)(p7 & 0x3FFFFu) * D + lane]);
            atomicAdd(&accs[(p0 >> 18) * D + lane], g0);
            atomicAdd(&accs[(p1 >> 18) * D + lane], g1);
            atomicAdd(&accs[(p2 >> 18) * D + lane], g2);
            atomicAdd(&accs[(p3 >> 18) * D + lane], g3);
            atomicAdd(&accs[(p4 >> 18) * D + lane], g4);
            atomicAdd(&accs[(p5 >> 18) * D + lane], g5);
            atomicAdd(&accs[(p6 >> 18) * D + lane], g6);
            atomicAdd(&accs[(p7 >> 18) * D + lane], g7);
        } else {
            for (int j = 0; j < n; ++j) {
                unsigned int p = csr_pk[e0 + j];
                atomicAdd(&accs[(p >> 18) * D + lane],
                          bf2f(hs16[(size_t)(p & 0x3FFFFu) * D + lane]));
            }
        }
    }
    __syncthreads();

    const float bl = bias[lane];
    for (int r = w; r < rows; r += 8) {
        int d = rs + r;
        float v = fmaf(accs[r * D + lane] + bf2f(hs16[(size_t)d * D + lane]),
                       dinv[d], bl);
        size_t idx = (size_t)d * D + lane;
        if (LAST) {
            acc[idx] = (acc[idx] + v) * scale;
        } else {
            acc[idx] = acc[idx] + v;
            val16[idx] = f2bf(v);
        }
    }
}

extern "C" void kernel_launch(void* const* d_in, const int* in_sizes, int n_in,
                              void* d_out, int out_size, void* d_ws, size_t ws_size,
                              hipStream_t stream) {
    const int* ei      = (const int*)d_in[0];
    const float* uemb  = (const float*)d_in[1];
    const float* iemb  = (const float*)d_in[2];
    const float* Ws    = (const float*)d_in[3];
    const float* bs    = (const float*)d_in[4];

    const int E = in_sizes[0] / 2;
    const int U = in_sizes[1] / D;
    const int I = in_sizes[2] / D;
    const int N = U + I;
    const int ND = N * D;
    const unsigned long long M = ((1ULL << 48) + (unsigned long long)N - 1) / (unsigned long long)N;

    unsigned short* X = (unsigned short*)d_ws;            // [N, D] bf16 (hs)
    unsigned short* Y = X + ND;                           // [N, D] bf16 (val)
    float* dinv    = (float*)(Y + ND);                    // [N]
    unsigned int* csr_pk = (unsigned int*)(dinv + N);     // [E] (ld<<18)|src, band-major
    unsigned int* packed = csr_pk + E;                    // [E] staging
    int*   bcount  = (int*)(packed + E);                  // [NBUK]
    int*   bbase   = bcount + NBUK;                       // [NBUK+1]
    int*   gfill   = bbase + NBUK + 1;                    // [NBUK]

    float* acc = (float*)d_out;                           // [N, D]

    // ---- build bucketed, band-major edge list ----
    hipMemsetAsync(bcount, 0, NBUK * sizeof(int), stream);
    k_bucket_hist<<<512, 256, 0, stream>>>(ei, bcount, E, M);
    k_scan_buckets<<<1, 512, 0, stream>>>(bcount, bbase, gfill, E);
    k_bucket_scatter<<<(E + TILE_E - 1) / TILE_E, 512, 0, stream>>>(ei, bbase, gfill,
                                                                   packed, E, M, N);
    k_build_fine<<<NBUK, 256, 0, stream>>>(packed, bbase, dinv, csr_pk, N);

    // ---- layer 0 GEMM (+ acc = x0): emb -> X = hs1 ----
    k_gemm<true><<<1024, 256, 0, stream>>>(uemb, iemb, U, nullptr, Ws, dinv, X, acc, N);

    // layer 1: X -> Y (val1 bf16), acc += val1
    k_agg_lds<false><<<NBUK, 512, 0, stream>>>(csr_pk, bbase, X, dinv, bs, Y, acc, 1.0f, N);
    // gemm: Y -> X = hs2
    k_gemm<false><<<1024, 256, 0, stream>>>(nullptr, nullptr, U, Y,
                                            Ws + (size_t)1 * D * D, dinv, X, acc, N);
    // layer 2: X -> Y (val2), acc += val2
    k_agg_lds<false><<<NBUK, 512, 0, stream>>>(csr_pk, bbase, X, dinv, bs + D, Y, acc, 1.0f, N);
    // gemm: Y -> X = hs3
    k_gemm<false><<<1024, 256, 0, stream>>>(nullptr, nullptr, U, Y,
                                            Ws + (size_t)2 * D * D, dinv, X, acc, N);
    // layer 3 (last): X -> acc = (acc + val3) * 0.25
    k_agg_lds<true><<<NBUK, 512, 0, stream>>>(csr_pk, bbase, X, dinv, bs + 2 * D,
                                              nullptr, acc, 0.25f, N);
}

// Round 10
// 394.752 us; speedup vs baseline: 6.3160x; 6.3160x over previous
//
#include <hip/hip_runtime.h>

constexpr int D = 64;
constexpr int BUK_SHIFT = 9;            // 512 dst nodes per bucket
constexpr int BUK_NODES = 1 << BUK_SHIFT;
constexpr int MAX_NBUK = 320;           // supports N <= 163840
constexpr int TILE_E = 4096;            // edges per scatter block (512 thr x 8)

typedef __attribute__((ext_vector_type(8))) short short8;   // 8 bf16 (4 VGPRs)
typedef __attribute__((ext_vector_type(4))) float f32x4;

__device__ inline unsigned short f2bf(float f) {   // RNE f32->bf16
    unsigned int u = __float_as_uint(f);
    u += 0x7FFFu + ((u >> 16) & 1u);
    return (unsigned short)(u >> 16);
}
__device__ inline float bf2f(unsigned short s) {
    return __uint_as_float(((unsigned int)s) << 16);
}

// ---------- 1. histogram of coarse buckets (dst >> BUK_SHIFT) ----------
__global__ __launch_bounds__(256) void k_bucket_hist(const int* __restrict__ ei,
                                                     int* __restrict__ bcount,
                                                     int E, int nbuk) {
    __shared__ int h[MAX_NBUK];
    for (int i = threadIdx.x; i < nbuk; i += blockDim.x) h[i] = 0;
    __syncthreads();
    int stride = gridDim.x * blockDim.x;
    for (int e = blockIdx.x * blockDim.x + threadIdx.x; e < E; e += stride)
        atomicAdd(&h[ei[E + e] >> BUK_SHIFT], 1);
    __syncthreads();
    for (int i = threadIdx.x; i < nbuk; i += blockDim.x)
        if (h[i]) atomicAdd(&bcount[i], h[i]);
}

// ---------- 2. scan bucket counts -> bbase; zero gfill; rowptr[N]=E ----------
__global__ __launch_bounds__(512) void k_scan_buckets(const int* __restrict__ bcount,
                                                      int* __restrict__ bbase,
                                                      int* __restrict__ gfill,
                                                      int* __restrict__ rowptr,
                                                      int nbuk, int N, int E) {
    __shared__ int sc[512];
    int tid = threadIdx.x;
    int v = (tid < nbuk) ? bcount[tid] : 0;
    sc[tid] = v;
    __syncthreads();
    for (int off = 1; off < 512; off <<= 1) {
        int t = (tid >= off) ? sc[tid - off] : 0;
        __syncthreads();
        sc[tid] += t;
        __syncthreads();
    }
    if (tid < nbuk) { bbase[tid] = sc[tid] - v; gfill[tid] = 0; }
    if (tid == 0) { bbase[nbuk] = E; rowptr[N] = E; }
}

// ---------- 3. scatter edges into coarse buckets (packed u32) ----------
__global__ __launch_bounds__(512) void k_bucket_scatter(const int* __restrict__ ei,
                                                        const int* __restrict__ bbase,
                                                        int* __restrict__ gfill,
                                                        unsigned int* __restrict__ packed,
                                                        int E, int nbuk) {
    __shared__ int hist[MAX_NBUK], base[MAX_NBUK], fil[MAX_NBUK];
    const int tid = threadIdx.x;
    for (int i = tid; i < nbuk; i += 512) hist[i] = 0;
    __syncthreads();

    const int t0 = blockIdx.x * TILE_E;
    int bk[8];
    unsigned int vv[8];
#pragma unroll
    for (int j = 0; j < 8; ++j) {
        int e = t0 + tid + j * 512;
        bk[j] = -1;
        if (e < E) {
            int src = ei[e];
            int dst = ei[E + e];
            bk[j] = dst >> BUK_SHIFT;
            vv[j] = ((unsigned int)(dst & (BUK_NODES - 1)) << 18) | (unsigned int)src;
            atomicAdd(&hist[bk[j]], 1);
        }
    }
    __syncthreads();
    for (int i = tid; i < nbuk; i += 512) {
        if (hist[i]) base[i] = atomicAdd(&gfill[i], hist[i]);
        fil[i] = 0;
    }
    __syncthreads();
#pragma unroll
    for (int j = 0; j < 8; ++j) {
        if (bk[j] >= 0) {
            int b = bk[j];
            int pos = bbase[b] + base[b] + atomicAdd(&fil[b], 1);
            packed[pos] = vv[j];
        }
    }
}

// ---------- 4. per-bucket: local hist -> rowptr, dinv, ordered csr_src ----------
__global__ __launch_bounds__(256) void k_build_csr(const unsigned int* __restrict__ packed,
                                                   const int* __restrict__ bbase,
                                                   int* __restrict__ rowptr,
                                                   float* __restrict__ dinv,
                                                   int* __restrict__ csr_src,
                                                   int N) {
    __shared__ int hist[BUK_NODES], rp[BUK_NODES], fil[BUK_NODES];
    const int b = blockIdx.x;
    const int s = bbase[b], t = bbase[b + 1];
    const int tid = threadIdx.x;
    for (int i = tid; i < BUK_NODES; i += 256) hist[i] = 0;
    __syncthreads();
    for (int e = s + tid; e < t; e += 256)
        atomicAdd(&hist[packed[e] >> 18], 1);
    __syncthreads();
    if (tid == 0) {
        int run = 0;
        for (int i = 0; i < BUK_NODES; ++i) { rp[i] = run; run += hist[i]; }
    }
    __syncthreads();
    const int dbase = b << BUK_SHIFT;
    for (int ld = tid; ld < BUK_NODES; ld += 256) {
        int d = dbase + ld;
        if (d < N) {
            rowptr[d] = s + rp[ld];
            dinv[d] = rsqrtf((float)(hist[ld] + 1));   // +1 self-loop
        }
        fil[ld] = 0;
    }
    __syncthreads();
    for (int e = s + tid; e < t; e += 256) {
        unsigned int v = packed[e];
        int ld = v >> 18;
        int pos = s + rp[ld] + atomicAdd(&fil[ld], 1);
        csr_src[pos] = (int)(v & 0x3FFFFu);
    }
}

// ------- MFMA GEMM: hs_out = bf16((xin @ W)*dinv) -------
template <bool F32IN>
__global__ __launch_bounds__(256) void k_gemm(const float* __restrict__ u,
                                              const float* __restrict__ it,
                                              int U,
                                              const unsigned short* __restrict__ xin16,
                                              const float* __restrict__ W,
                                              const float* __restrict__ dinv,
                                              unsigned short* __restrict__ hs_out,
                                              int N) {
    const int lane = threadIdx.x & 63;
    const int g = lane >> 4;
    const int lr = lane & 15;

    short8 bf[4][2];
#pragma unroll
    for (int ct = 0; ct < 4; ++ct)
#pragma unroll
        for (int kb = 0; kb < 2; ++kb) {
            short8 v;
            int c = ct * 16 + lr;
#pragma unroll
            for (int e = 0; e < 4; ++e) {
                int k0 = kb * 32 + g * 4 + e;
                v[e]     = (short)f2bf(W[k0 * D + c]);
                v[e + 4] = (short)f2bf(W[(k0 + 16) * D + c]);
            }
            bf[ct][kb] = v;
        }

    const int wid = blockIdx.x * (blockDim.x >> 6) + (threadIdx.x >> 6);
    const int nw = gridDim.x * (blockDim.x >> 6);

    for (int rb = wid * 16; rb < N; rb += nw * 16) {
        int row = rb + lr;                     // A-operand row for this lane
        bool ok = (row < N);
        short8 af[2];
        if (F32IN) {
            const float* xr = nullptr;
            if (ok) xr = (row < U) ? (u + (size_t)row * D)
                                   : (it + (size_t)(row - U) * D);
#pragma unroll
            for (int kb = 0; kb < 2; ++kb) {
                float4 q0 = ok ? *(const float4*)(xr + kb * 32 + g * 4)
                               : float4{0.f, 0.f, 0.f, 0.f};
                float4 q1 = ok ? *(const float4*)(xr + kb * 32 + 16 + g * 4)
                               : float4{0.f, 0.f, 0.f, 0.f};
                short8 v;
                v[0] = (short)f2bf(q0.x); v[1] = (short)f2bf(q0.y);
                v[2] = (short)f2bf(q0.z); v[3] = (short)f2bf(q0.w);
                v[4] = (short)f2bf(q1.x); v[5] = (short)f2bf(q1.y);
                v[6] = (short)f2bf(q1.z); v[7] = (short)f2bf(q1.w);
                af[kb] = v;
            }
        } else {
            const unsigned short* xr = xin16 + (size_t)row * D;
#pragma unroll
            for (int kb = 0; kb < 2; ++kb) {
                short4 q0 = ok ? *(const short4*)(xr + kb * 32 + g * 4)
                               : short4{0, 0, 0, 0};
                short4 q1 = ok ? *(const short4*)(xr + kb * 32 + 16 + g * 4)
                               : short4{0, 0, 0, 0};
                short8 v;
                v[0] = q0.x; v[1] = q0.y; v[2] = q0.z; v[3] = q0.w;
                v[4] = q1.x; v[5] = q1.y; v[6] = q1.z; v[7] = q1.w;
                af[kb] = v;
            }
        }

        float di[4];
#pragma unroll
        for (int r = 0; r < 4; ++r) {
            int ro = rb + g * 4 + r;
            di[r] = (ro < N) ? dinv[ro] : 0.f;
        }

#pragma unroll
        for (int ct = 0; ct < 4; ++ct) {
            f32x4 a = {0.f, 0.f, 0.f, 0.f};
            a = __builtin_amdgcn_mfma_f32_16x16x32_bf16(af[0], bf[ct][0], a, 0, 0, 0);
            a = __builtin_amdgcn_mfma_f32_16x16x32_bf16(af[1], bf[ct][1], a, 0, 0, 0);
#pragma unroll
            for (int r = 0; r < 4; ++r) {
                int ro = rb + g * 4 + r;
                if (ro < N)
                    hs_out[(size_t)ro * D + ct * 16 + lr] = f2bf(a[r] * di[r]);
            }
        }
    }
}

// ------- val16 = bf16( dinv*(hs[d] + sum hs[src]) + b ); 16-deep gather pipe -------
__global__ __launch_bounds__(256) void k_aggregate(const int* __restrict__ rowptr,
                                                   const int* __restrict__ csr_src,
                                                   const unsigned short* __restrict__ hs16,
                                                   const float* __restrict__ dinv,
                                                   const float* __restrict__ b,
                                                   unsigned short* __restrict__ val16,
                                                   int N) {
    int w = (int)((blockIdx.x * (size_t)blockDim.x + threadIdx.x) >> 6);
    int lane = threadIdx.x & 63;
    if (w >= N) return;
    int beg = rowptr[w], end = rowptr[w + 1];
    const float di = dinv[w];
    const float bl = b[lane];
    float s[8];
    s[0] = bf2f(hs16[(size_t)w * D + lane]);   // self-loop (already * dinv)
#pragma unroll
    for (int j = 1; j < 8; ++j) s[j] = 0.f;

    int e = beg;
    for (; e + 16 <= end; e += 16) {           // 16 gathers in flight
        int idx[16];
#pragma unroll
        for (int j = 0; j < 16; ++j) idx[j] = csr_src[e + j];
        float g[16];
#pragma unroll
        for (int j = 0; j < 16; ++j) g[j] = bf2f(hs16[(size_t)idx[j] * D + lane]);
#pragma unroll
        for (int j = 0; j < 16; ++j) s[j & 7] += g[j];
    }
    if (e + 8 <= end) {
        int idx[8];
#pragma unroll
        for (int j = 0; j < 8; ++j) idx[j] = csr_src[e + j];
#pragma unroll
        for (int j = 0; j < 8; ++j) s[j] += bf2f(hs16[(size_t)idx[j] * D + lane]);
        e += 8;
    }
    if (e + 4 <= end) {
        int idx[4];
#pragma unroll
        for (int j = 0; j < 4; ++j) idx[j] = csr_src[e + j];
#pragma unroll
        for (int j = 0; j < 4; ++j) s[j] += bf2f(hs16[(size_t)idx[j] * D + lane]);
        e += 4;
    }
    for (; e < end; ++e) s[0] += bf2f(hs16[(size_t)csr_src[e] * D + lane]);

    float sum = ((s[0] + s[1]) + (s[2] + s[3])) + ((s[4] + s[5]) + (s[6] + s[7]));
    val16[(size_t)w * D + lane] = f2bf(fmaf(sum, di, bl));
}

// ------- final: acc = (x0 + v1 + v2 + v3) * 0.25 -------
__global__ __launch_bounds__(256) void k_final(const float* __restrict__ u,
                                               const float* __restrict__ it,
                                               const unsigned short* __restrict__ v1,
                                               const unsigned short* __restrict__ v2,
                                               const unsigned short* __restrict__ v3,
                                               float* __restrict__ acc,
                                               int UD, int total) {
    int i = (blockIdx.x * blockDim.x + threadIdx.x) * 8;
    const int stride = gridDim.x * blockDim.x * 8;
    for (; i < total; i += stride) {
        const float* x0 = (i < UD) ? (u + i) : (it + (i - UD));
        float4 a0 = *(const float4*)(x0);
        float4 a1 = *(const float4*)(x0 + 4);
        short8 w1 = *(const short8*)(v1 + i);
        short8 w2 = *(const short8*)(v2 + i);
        short8 w3 = *(const short8*)(v3 + i);
        float o[8];
        o[0] = a0.x; o[1] = a0.y; o[2] = a0.z; o[3] = a0.w;
        o[4] = a1.x; o[5] = a1.y; o[6] = a1.z; o[7] = a1.w;
#pragma unroll
        for (int j = 0; j < 8; ++j) {
            o[j] = (o[j] + bf2f((unsigned short)w1[j])
                         + bf2f((unsigned short)w2[j])
                         + bf2f((unsigned short)w3[j])) * 0.25f;
        }
        float4 r0 = {o[0], o[1], o[2], o[3]};
        float4 r1 = {o[4], o[5], o[6], o[7]};
        *(float4*)(acc + i) = r0;
        *(float4*)(acc + i + 4) = r1;
    }
}

extern "C" void kernel_launch(void* const* d_in, const int* in_sizes, int n_in,
                              void* d_out, int out_size, void* d_ws, size_t ws_size,
                              hipStream_t stream) {
    const int* ei      = (const int*)d_in[0];
    const float* uemb  = (const float*)d_in[1];
    const float* iemb  = (const float*)d_in[2];
    const float* Ws    = (const float*)d_in[3];
    const float* bs    = (const float*)d_in[4];

    const int E = in_sizes[0] / 2;
    const int U = in_sizes[1] / D;
    const int I = in_sizes[2] / D;
    const int N = U + I;
    const int ND = N * D;
    const int nbuk = (N + BUK_NODES - 1) >> BUK_SHIFT;

    unsigned short* X  = (unsigned short*)d_ws;           // [N, D] bf16 (hs, reused)
    unsigned short* V1 = X + ND;                          // [N, D] bf16
    unsigned short* V2 = V1 + ND;                         // [N, D] bf16
    unsigned short* V3 = V2 + ND;                         // [N, D] bf16
    float* dinv    = (float*)(V3 + ND);                   // [N]
    int*   csr_src = (int*)(dinv + N);                    // [E]
    unsigned int* packed = (unsigned int*)(csr_src + E);  // [E]
    int*   rowptr  = (int*)(packed + E);                  // [N+1]
    int*   bcount  = rowptr + N + 1;                      // [nbuk]
    int*   bbase   = bcount + MAX_NBUK;                   // [nbuk+1]
    int*   gfill   = bbase + MAX_NBUK + 1;                // [nbuk]

    float* acc = (float*)d_out;                           // [N, D]

    // ---- build CSR ----
    hipMemsetAsync(bcount, 0, nbuk * sizeof(int), stream);
    k_bucket_hist<<<512, 256, 0, stream>>>(ei, bcount, E, nbuk);
    k_scan_buckets<<<1, 512, 0, stream>>>(bcount, bbase, gfill, rowptr, nbuk, N, E);
    k_bucket_scatter<<<(E + TILE_E - 1) / TILE_E, 512, 0, stream>>>(ei, bbase, gfill,
                                                                   packed, E, nbuk);
    k_build_csr<<<nbuk, 256, 0, stream>>>(packed, bbase, rowptr, dinv, csr_src, N);

    // ---- layers (deferred acc) ----
    const int nagg = (N + 3) / 4;
    // gemm0: emb -> X = hs1
    k_gemm<true><<<1024, 256, 0, stream>>>(uemb, iemb, U, nullptr, Ws, dinv, X, N);
    // agg1: X -> V1
    k_aggregate<<<nagg, 256, 0, stream>>>(rowptr, csr_src, X, dinv, bs, V1, N);
    // gemm1: V1 -> X = hs2
    k_gemm<false><<<1024, 256, 0, stream>>>(nullptr, nullptr, U, V1,
                                            Ws + (size_t)1 * D * D, dinv, X, N);
    // agg2: X -> V2
    k_aggregate<<<nagg, 256, 0, stream>>>(rowptr, csr_src, X, dinv, bs + D, V2, N);
    // gemm2: V2 -> X = hs3
    k_gemm<false><<<1024, 256, 0, stream>>>(nullptr, nullptr, U, V2,
                                            Ws + (size_t)2 * D * D, dinv, X, N);
    // agg3: X -> V3
    k_aggregate<<<nagg, 256, 0, stream>>>(rowptr, csr_src, X, dinv, bs + 2 * D, V3, N);
    // final: acc = (x0 + v1 + v2 + v3) / 4
    k_final<<<2048, 256, 0, stream>>>(uemb, iemb, V1, V2, V3, acc, U * D, ND);
}